// Round 1
// baseline (157.834 us; speedup 1.0000x reference)
//
#include <hip/hip_runtime.h>
#include <hip/hip_bf16.h>

#define B_HALF 4096
#define N_TOT  8192
#define D_DIM  256
#define CSPLIT 8
#define BT     128
#define NTILES 8   /* (N_TOT/CSPLIT)/BT */

typedef short bf16x8 __attribute__((ext_vector_type(8)));
typedef float f32x4  __attribute__((ext_vector_type(4)));

#define NEG_INF (-__builtin_inff())

__device__ __forceinline__ unsigned short f2b(float f) {
  __hip_bfloat16 h = __float2bfloat16(f);
  return *reinterpret_cast<unsigned short*>(&h);
}

// reps = [zjs; zis] as bf16, row-major [N_TOT][D_DIM]. Block 0 zeroes out[0..1].
__global__ __launch_bounds__(256) void convert_k(const float* __restrict__ zis,
                                                 const float* __restrict__ zjs,
                                                 unsigned short* __restrict__ reps,
                                                 float* __restrict__ out) {
  size_t idx = ((size_t)blockIdx.x * 256 + threadIdx.x) * 4;
  const float* src = (idx < (size_t)B_HALF * D_DIM) ? (zjs + idx)
                                                    : (zis + (idx - (size_t)B_HALF * D_DIM));
  float4 v = *reinterpret_cast<const float4*>(src);
  ushort4 o;
  o.x = f2b(v.x); o.y = f2b(v.y); o.z = f2b(v.z); o.w = f2b(v.w);
  *reinterpret_cast<ushort4*>(reps + idx) = o;
  if (blockIdx.x == 0 && threadIdx.x < 2) out[threadIdx.x] = 0.0f;
}

// Stage a 128x256 bf16 tile (64KB) global->LDS with XOR-swizzled source so that
// LDS dest stays linear (global_load_lds requirement) and fragment ds_read_b128
// is ~conflict-free. phys chunk (row, c) holds logical chunk c ^ (row&7).
__device__ __forceinline__ void stage_tile(short* lds, const unsigned short* gsrc) {
  const int t = threadIdx.x;
  #pragma unroll
  for (int it = 0; it < 16; ++it) {
    int pc  = it * 256 + t;      // 16B-chunk id 0..4095 (linear in lane order)
    int row = pc >> 5;           // 0..127
    int c   = pc & 31;
    int lc  = c ^ (row & 7);
    const unsigned short* src = gsrc + row * D_DIM + lc * 8;
    short* dst = lds + pc * 8;
    __builtin_amdgcn_global_load_lds((const __attribute__((address_space(1))) void*)src,
                                     (__attribute__((address_space(3))) void*)dst,
                                     16, 0, 0);
  }
}

__global__ __launch_bounds__(256) void ntxent_main(const unsigned short* __restrict__ reps,
                                                   float* __restrict__ part_m,
                                                   float* __restrict__ part_s,
                                                   float* __restrict__ pos_out) {
  __shared__ short As[BT * D_DIM];  // 64KB
  __shared__ short Bs[BT * D_DIM];  // 64KB

  const int tid  = threadIdx.x;
  const int lane = tid & 63;
  const int l15  = lane & 15;
  const int l4   = lane >> 4;
  const int wave = tid >> 6;
  const int wm   = wave >> 1;   // 2x2 wave grid, 64x64 per wave
  const int wn   = wave & 1;

  const int rb    = (int)blockIdx.x >> 3;   // 64 row blocks
  const int cs    = (int)blockIdx.x & 7;    // 8 column splits
  const int r0    = rb * BT;
  const int cbase = cs * (N_TOT / CSPLIT);

  stage_tile(As, reps + (size_t)r0 * D_DIM);
  stage_tile(Bs, reps + (size_t)cbase * D_DIM);

  float mrun[4][4], srun[4][4], posv[4][4];   // [mf][reg] row state (replicated over 16-lane group)
  #pragma unroll
  for (int mf = 0; mf < 4; ++mf)
    #pragma unroll
    for (int r = 0; r < 4; ++r) { mrun[mf][r] = NEG_INF; srun[mf][r] = 0.f; posv[mf][r] = NEG_INF; }

  f32x4 acc[4][4];

  for (int ct = 0; ct < NTILES; ++ct) {
    __syncthreads();   // staged tile ready (syncthreads drains vmcnt)

    const f32x4 vzero = {0.f, 0.f, 0.f, 0.f};
    #pragma unroll
    for (int mf = 0; mf < 4; ++mf)
      #pragma unroll
      for (int nf = 0; nf < 4; ++nf) acc[mf][nf] = vzero;

    #pragma unroll
    for (int ks = 0; ks < 8; ++ks) {
      const int kc = ks * 4 + l4;           // 16B k-chunk index
      bf16x8 af[4], bfr[4];
      #pragma unroll
      for (int mf = 0; mf < 4; ++mf) {
        int row = wm * 64 + mf * 16 + l15;
        af[mf] = *reinterpret_cast<const bf16x8*>(&As[row * D_DIM + ((kc ^ (row & 7)) << 3)]);
      }
      #pragma unroll
      for (int nf = 0; nf < 4; ++nf) {
        int row = wn * 64 + nf * 16 + l15;
        bfr[nf] = *reinterpret_cast<const bf16x8*>(&Bs[row * D_DIM + ((kc ^ (row & 7)) << 3)]);
      }
      #pragma unroll
      for (int mf = 0; mf < 4; ++mf)
        #pragma unroll
        for (int nf = 0; nf < 4; ++nf)
          acc[mf][nf] = __builtin_amdgcn_mfma_f32_16x16x32_bf16(af[mf], bfr[nf], acc[mf][nf], 0, 0, 0);
    }

    __syncthreads();   // all waves done reading Bs
    if (ct + 1 < NTILES)
      stage_tile(Bs, reps + (size_t)(cbase + (ct + 1) * BT) * D_DIM);  // hides under epilogue

    // ---- fused online-softmax epilogue over this 128-col tile ----
    const int c0 = cbase + ct * BT + wn * 64;
    #pragma unroll
    for (int mf = 0; mf < 4; ++mf) {
      #pragma unroll
      for (int r = 0; r < 4; ++r) {
        const int i    = r0 + wm * 64 + mf * 16 + l4 * 4 + r;   // C/D: row=(l>>4)*4+reg
        const int pcol = (i + B_HALF) & (N_TOT - 1);
        float tmax = NEG_INF;
        #pragma unroll
        for (int nf = 0; nf < 4; ++nf) {
          const int j = c0 + nf * 16 + l15;                     // C/D: col=lane&15
          float v = acc[mf][nf][r] * 2.0f;                      // 1/TEMPERATURE
          if (j == i)    v = NEG_INF;                           // mask diagonal
          if (j == pcol) posv[mf][r] = v;                       // capture positive (stays in lse)
          acc[mf][nf][r] = v;
          tmax = fmaxf(tmax, v);
        }
        #pragma unroll
        for (int off = 1; off < 16; off <<= 1)
          tmax = fmaxf(tmax, __shfl_xor(tmax, off, 16));
        const float mn = fmaxf(mrun[mf][r], tmax);
        srun[mf][r] *= __expf(mrun[mf][r] - mn);                // 0*0 at first tile, fine
        mrun[mf][r] = mn;
        float ts = 0.f;
        #pragma unroll
        for (int nf = 0; nf < 4; ++nf)
          ts += __expf(acc[mf][nf][r] - mn);                    // masked -> exp(-inf)=0
        #pragma unroll
        for (int off = 1; off < 16; off <<= 1)
          ts += __shfl_xor(ts, off, 16);
        srun[mf][r] += ts;
      }
    }
  }

  // write per-(row, split, wn) partials; pos written by its unique owner
  #pragma unroll
  for (int mf = 0; mf < 4; ++mf) {
    #pragma unroll
    for (int r = 0; r < 4; ++r) {
      float p = posv[mf][r];
      #pragma unroll
      for (int off = 1; off < 16; off <<= 1)
        p = fmaxf(p, __shfl_xor(p, off, 16));
      if (l15 == 0) {
        const int i = r0 + wm * 64 + mf * 16 + l4 * 4 + r;
        part_m[(i * CSPLIT + cs) * 2 + wn] = mrun[mf][r];
        part_s[(i * CSPLIT + cs) * 2 + wn] = srun[mf][r];
        if (p > -1e37f) pos_out[i] = p;
      }
    }
  }
}

__global__ __launch_bounds__(256) void finalize_k(const float* __restrict__ pm,
                                                  const float* __restrict__ ps,
                                                  const float* __restrict__ pv,
                                                  float* __restrict__ out) {
  const int row = blockIdx.x * 256 + threadIdx.x;
  float m = NEG_INF;
  #pragma unroll
  for (int s = 0; s < 16; ++s) m = fmaxf(m, pm[row * 16 + s]);
  float ss = 0.f;
  #pragma unroll
  for (int s = 0; s < 16; ++s) ss += ps[row * 16 + s] * __expf(pm[row * 16 + s] - m);
  const float pos  = pv[row];
  float loss = m + __logf(ss) - pos;
  float hit  = (pos >= m) ? 1.0f : 0.0f;    // argmax==0 <=> pos is the global max

  #pragma unroll
  for (int off = 32; off; off >>= 1) {
    loss += __shfl_down(loss, off);
    hit  += __shfl_down(hit,  off);
  }
  __shared__ float redL[4], redH[4];
  const int wv = threadIdx.x >> 6;
  if ((threadIdx.x & 63) == 0) { redL[wv] = loss; redH[wv] = hit; }
  __syncthreads();
  if (threadIdx.x == 0) {
    float L = redL[0] + redL[1] + redL[2] + redL[3];
    float H = redH[0] + redH[1] + redH[2] + redH[3];
    atomicAdd(&out[0], L * (1.0f / 8192.0f));
    atomicAdd(&out[1], H * (1.0f / 8192.0f));
  }
}

extern "C" void kernel_launch(void* const* d_in, const int* in_sizes, int n_in,
                              void* d_out, int out_size, void* d_ws, size_t ws_size,
                              hipStream_t stream) {
  const float* zis = (const float*)d_in[0];
  const float* zjs = (const float*)d_in[1];
  float* out = (float*)d_out;

  char* ws = (char*)d_ws;
  unsigned short* reps = (unsigned short*)ws;                         // 4 MB
  float* part_m = (float*)(ws + 4u * 1024u * 1024u);                  // 512 KB
  float* part_s = (float*)(ws + 4u * 1024u * 1024u + 512u * 1024u);   // 512 KB
  float* pos_a  = (float*)(ws + 5u * 1024u * 1024u);                  // 32 KB
  (void)in_sizes; (void)n_in; (void)out_size; (void)ws_size;

  convert_k<<<2048, 256, 0, stream>>>(zis, zjs, reps, out);
  ntxent_main<<<512, 256, 0, stream>>>(reps, part_m, part_s, pos_a);
  finalize_k<<<32, 256, 0, stream>>>(part_m, part_s, pos_a, out);
}

// Round 2
// 120.449 us; speedup vs baseline: 1.3104x; 1.3104x over previous
//
#include <hip/hip_runtime.h>
#include <hip/hip_bf16.h>

#define N_TOT  8192
#define B_HALF 4096
#define D_DIM  256
#define CTW    64     /* B tile cols */
#define CT_N   8      /* tiles per block: 512 cols */

typedef short bf16x8 __attribute__((ext_vector_type(8)));
typedef float f32x4  __attribute__((ext_vector_type(4)));

#define NEG_INF (-__builtin_inff())
#define RSCALE  1.6986436f     /* sqrt(2*log2e): (s*a)|(s*b) = sim * 2/ln2 (logits in log2 units) */
#define LN2F    0.69314718056f

__device__ __forceinline__ float exp2_fast(float x) {
  float r;
  asm("v_exp_f32 %0, %1" : "=v"(r) : "v"(x));
  return r;
}

__device__ __forceinline__ unsigned short f2b(float f) {
  __hip_bfloat16 h = __float2bfloat16(f);
  return *reinterpret_cast<unsigned short*>(&h);
}

// reps = [zjs; zis] * RSCALE as bf16 [N_TOT][D_DIM]; block 0 zeroes out[0..1].
__global__ __launch_bounds__(256) void convert_k(const float* __restrict__ zis,
                                                 const float* __restrict__ zjs,
                                                 unsigned short* __restrict__ reps,
                                                 float* __restrict__ out) {
  size_t idx = ((size_t)blockIdx.x * 256 + threadIdx.x) * 4;
  const float* src = (idx < (size_t)B_HALF * D_DIM) ? (zjs + idx)
                                                    : (zis + (idx - (size_t)B_HALF * D_DIM));
  float4 v = *reinterpret_cast<const float4*>(src);
  ushort4 o;
  o.x = f2b(v.x * RSCALE); o.y = f2b(v.y * RSCALE);
  o.z = f2b(v.z * RSCALE); o.w = f2b(v.w * RSCALE);
  *reinterpret_cast<ushort4*>(reps + idx) = o;
  if (blockIdx.x == 0 && threadIdx.x < 2) out[threadIdx.x] = 0.0f;
}

// Stage a 64x256 bf16 tile (32KB): linear LDS dest (global_load_lds requirement),
// XOR-swizzled global source so fragment ds_read_b128 is near conflict-free.
__device__ __forceinline__ void stage_tile(short* lds, const unsigned short* gsrc, int tid) {
  #pragma unroll
  for (int it = 0; it < 4; ++it) {
    int pc  = it * 512 + tid;          // 16B chunk id, 0..2047
    int row = pc >> 5;                 // 0..63
    int lc  = (pc & 31) ^ (row & 7);   // swizzled source chunk
    const unsigned short* src = gsrc + row * D_DIM + lc * 8;
    short* dst = lds + pc * 8;
    __builtin_amdgcn_global_load_lds((const __attribute__((address_space(1))) void*)src,
                                     (__attribute__((address_space(3))) void*)dst, 16, 0, 0);
  }
}

// Grid 256 = 16 row-blocks (512 rows) x 16 col-splits (512 cols). 8 waves/block,
// wave wm owns rows [r0+wm*64, +64) with A resident in VGPRs (full K).
__global__ __launch_bounds__(512, 2) void ntxent_main(const unsigned short* __restrict__ reps,
                                                      float* __restrict__ part_m,
                                                      float* __restrict__ part_s,
                                                      float* __restrict__ pos_out) {
  __shared__ short Bs[2][CTW * D_DIM];   // 2 x 32KB double buffer

  const int tid  = threadIdx.x;
  const int lane = tid & 63;
  const int l15  = lane & 15;
  const int l4   = lane >> 4;
  const int wm   = tid >> 6;             // wave index 0..7

  const int rb    = (int)blockIdx.x & 15;
  const int cs    = (int)blockIdx.x >> 4;
  const int r0    = rb * 512;
  const int cbase = cs * 512;

  // A fragments: af[mf][kc], row = r0+wm*64+mf*16+l15, k-chunk kc*4+l4 (8 bf16)
  bf16x8 af[4][8];
  #pragma unroll
  for (int mf = 0; mf < 4; ++mf) {
    const unsigned short* arow = reps + (size_t)(r0 + wm * 64 + mf * 16 + l15) * D_DIM;
    #pragma unroll
    for (int kc = 0; kc < 8; ++kc)
      af[mf][kc] = *reinterpret_cast<const bf16x8*>(arow + (kc * 4 + l4) * 8);
  }

  stage_tile(Bs[0], reps + (size_t)cbase * D_DIM, tid);

  float mrun[4][4], srun[4][4], posv[4];
  #pragma unroll
  for (int mf = 0; mf < 4; ++mf) {
    posv[mf] = NEG_INF;
    #pragma unroll
    for (int r = 0; r < 4; ++r) { mrun[mf][r] = NEG_INF; srun[mf][r] = 0.f; }
  }

  // diagonal / positive land in exactly one (block, wave==ct) pair, at nf==mf,
  // owner lane l15 == l4*4+r  (since 512 | 4096 and tile width == wave rows)
  const bool diag_blk = (cs == rb);
  const bool pos_blk  = (cs == ((rb + 8) & 15));

  int cur = 0;
  for (int ct = 0; ct < CT_N; ++ct) {
    __syncthreads();                    // Bs[cur] staged; prev reads of Bs[cur^1] done
    if (ct + 1 < CT_N)
      stage_tile(Bs[cur ^ 1], reps + (size_t)(cbase + (ct + 1) * CTW) * D_DIM, tid);

    const f32x4 vz = {0.f, 0.f, 0.f, 0.f};
    f32x4 acc[4][4];
    #pragma unroll
    for (int mf = 0; mf < 4; ++mf)
      #pragma unroll
      for (int nf = 0; nf < 4; ++nf) acc[mf][nf] = vz;

    #pragma unroll
    for (int ks = 0; ks < 8; ++ks) {
      bf16x8 bfr[4];
      #pragma unroll
      for (int nf = 0; nf < 4; ++nf) {
        int row = nf * 16 + l15;
        bfr[nf] = *reinterpret_cast<const bf16x8*>(
            &Bs[cur][row * D_DIM + (((ks * 4 + l4) ^ (row & 7)) << 3)]);
      }
      #pragma unroll
      for (int mf = 0; mf < 4; ++mf)
        #pragma unroll
        for (int nf = 0; nf < 4; ++nf)
          acc[mf][nf] = __builtin_amdgcn_mfma_f32_16x16x32_bf16(af[mf][ks], bfr[nf],
                                                                acc[mf][nf], 0, 0, 0);
    }

    if (diag_blk && ct == wm) {         // mask self-similarity
      #pragma unroll
      for (int mf = 0; mf < 4; ++mf)
        #pragma unroll
        for (int r = 0; r < 4; ++r)
          if (l15 == l4 * 4 + r) acc[mf][mf][r] = NEG_INF;
    }
    if (pos_blk && ct == wm) {          // capture positive (stays inside the lse)
      #pragma unroll
      for (int mf = 0; mf < 4; ++mf)
        #pragma unroll
        for (int r = 0; r < 4; ++r)
          if (l15 == l4 * 4 + r) posv[mf] = acc[mf][mf][r];
    }

    // per-lane online logsumexp (log2 domain), no cross-lane ops here
    #pragma unroll
    for (int mf = 0; mf < 4; ++mf)
      #pragma unroll
      for (int r = 0; r < 4; ++r) {
        float u0 = acc[mf][0][r], u1 = acc[mf][1][r];
        float u2 = acc[mf][2][r], u3 = acc[mf][3][r];
        float mx = fmaxf(fmaxf(u0, u1), fmaxf(u2, u3));
        float mn = fmaxf(mrun[mf][r], mx);
        float sc = exp2_fast(mrun[mf][r] - mn);   // 0 on first tile (-inf), 1 if unchanged
        float es = exp2_fast(u0 - mn) + exp2_fast(u1 - mn)
                 + exp2_fast(u2 - mn) + exp2_fast(u3 - mn);
        srun[mf][r] = fmaf(srun[mf][r], sc, es);
        mrun[mf][r] = mn;
      }

    cur ^= 1;
  }

  // merge the 16 lanes of each l4-group (same rows, disjoint col subsets), write partials
  #pragma unroll
  for (int mf = 0; mf < 4; ++mf) {
    #pragma unroll
    for (int r = 0; r < 4; ++r) {
      float m = mrun[mf][r], s = srun[mf][r];
      #pragma unroll
      for (int off = 1; off < 16; off <<= 1) {
        float mo = __shfl_xor(m, off, 16);
        float so = __shfl_xor(s, off, 16);
        float mn = fmaxf(m, mo);
        s = fmaf(s, exp2_fast(m - mn), so * exp2_fast(mo - mn));
        m = mn;
      }
      const int i = r0 + wm * 64 + mf * 16 + l4 * 4 + r;
      if (l15 == 0) {
        part_m[i * 16 + cs] = m;
        part_s[i * 16 + cs] = s;
      }
      if (pos_blk) {
        float p = __shfl(posv[mf], (lane & 48) + l4 * 4 + r, 64);  // pull from owner lane
        if (l15 == 0) pos_out[i] = p;
      }
    }
  }
}

__global__ __launch_bounds__(256) void finalize_k(const float* __restrict__ pm,
                                                  const float* __restrict__ ps,
                                                  const float* __restrict__ pv,
                                                  float* __restrict__ out) {
  const int row = blockIdx.x * 256 + threadIdx.x;
  float m = NEG_INF;
  #pragma unroll
  for (int s = 0; s < 16; ++s) m = fmaxf(m, pm[row * 16 + s]);
  float ss = 0.f;
  #pragma unroll
  for (int s = 0; s < 16; ++s) ss += ps[row * 16 + s] * exp2_fast(pm[row * 16 + s] - m);
  const float posu = pv[row];
  float loss = (m + __log2f(ss) - posu) * LN2F;   // back to nats
  float hit  = (posu >= m) ? 1.0f : 0.0f;         // argmax==0 <=> pos is global max

  #pragma unroll
  for (int off = 32; off; off >>= 1) {
    loss += __shfl_down(loss, off);
    hit  += __shfl_down(hit,  off);
  }
  __shared__ float redL[4], redH[4];
  const int wv = threadIdx.x >> 6;
  if ((threadIdx.x & 63) == 0) { redL[wv] = loss; redH[wv] = hit; }
  __syncthreads();
  if (threadIdx.x == 0) {
    float L = redL[0] + redL[1] + redL[2] + redL[3];
    float H = redH[0] + redH[1] + redH[2] + redH[3];
    atomicAdd(&out[0], L * (1.0f / 8192.0f));
    atomicAdd(&out[1], H * (1.0f / 8192.0f));
  }
}

extern "C" void kernel_launch(void* const* d_in, const int* in_sizes, int n_in,
                              void* d_out, int out_size, void* d_ws, size_t ws_size,
                              hipStream_t stream) {
  const float* zis = (const float*)d_in[0];
  const float* zjs = (const float*)d_in[1];
  float* out = (float*)d_out;

  char* ws = (char*)d_ws;
  unsigned short* reps = (unsigned short*)ws;                         // 4 MB
  float* part_m = (float*)(ws + 4u * 1024u * 1024u);                  // 512 KB
  float* part_s = (float*)(ws + 4u * 1024u * 1024u + 512u * 1024u);   // 512 KB
  float* pos_a  = (float*)(ws + 5u * 1024u * 1024u);                  // 32 KB
  (void)in_sizes; (void)n_in; (void)out_size; (void)ws_size;

  convert_k<<<2048, 256, 0, stream>>>(zis, zjs, reps, out);
  ntxent_main<<<256, 512, 0, stream>>>(reps, part_m, part_s, pos_a);
  finalize_k<<<32, 256, 0, stream>>>(part_m, part_s, pos_a, out);
}